// Round 6
// baseline (195.411 us; speedup 1.0000x reference)
//
#include <hip/hip_runtime.h>
#include <hip/hip_bf16.h>

// Problem constants (fixed by reference): B=8, C=128, N=M=4096, OUT=128
#define BATCH 8
#define CDIM 128
#define NDIM 4096

typedef __bf16 bf16x8 __attribute__((ext_vector_type(8)));
typedef float f32x4 __attribute__((ext_vector_type(4)));
typedef float f32x16 __attribute__((ext_vector_type(16)));
typedef unsigned u32x4 __attribute__((ext_vector_type(4)));

// workspace layout (bytes)
#define QT_OFF 0u                      // bf16 [8][4096][128]  normalized*log2e target_g, transposed
#define KT_OFF 8388608u                // bf16 [8][4096][128]  normalized input, transposed
#define VB_OFF 16777216u               // bf16 [8][128][4096]  raw input
#define WT_OFF 25165824u               // bf16 [128][128]      weight transposed: wT[o][c]
#define SC_OFF (WT_OFF + 32768u)       // f32 [128] scale = gamma*rsqrt(var+eps)
#define BI_OFF (SC_OFF + 512u)         // f32 [128] bias  = beta - mean*scale

__device__ __forceinline__ f32x4 mfma16(bf16x8 a, bf16x8 b, f32x4 c) {
    return __builtin_amdgcn_mfma_f32_16x16x32_bf16(a, b, c, 0, 0, 0);
}
__device__ __forceinline__ f32x16 mfma32(bf16x8 a, bf16x8 b, f32x16 c) {
    return __builtin_amdgcn_mfma_f32_32x32x16_bf16(a, b, c, 0, 0, 0);
}

__device__ __forceinline__ unsigned pack2bf(float a, float b) {
    unsigned short ul = __builtin_bit_cast(unsigned short, (__bf16)a);
    unsigned short uh = __builtin_bit_cast(unsigned short, (__bf16)b);
    return (unsigned)ul | ((unsigned)uh << 16);
}

__device__ __forceinline__ void glds16(const void* g, void* l) {
    __builtin_amdgcn_global_load_lds((__attribute__((address_space(1))) void*)(void*)g,
                                     (__attribute__((address_space(3))) void*)l, 16, 0, 0);
}

// ---------------------------------------------------------------------------
// Pass 1: per-column L2 normalize over C + transpose to [n][c] bf16.
// z==0: input -> Kt + Vb ; z==1: target_g -> Qt scaled by log2(e)
// (P = 2^(S*log2e) = e^S; softmax shift-invariance removes the -1).
// ---------------------------------------------------------------------------
__global__ __launch_bounds__(256) void prep_nt(const float* __restrict__ input,
                                               const float* __restrict__ tg,
                                               const float* __restrict__ wgt,
                                               const float* __restrict__ gamma,
                                               const float* __restrict__ beta,
                                               const float* __restrict__ mean,
                                               const float* __restrict__ var,
                                               void* __restrict__ ws) {
    __shared__ float Tt[64][129];     // [n-local][c], pitch 129
    __shared__ float psum[4][64];
    __shared__ float rn[64];
    const int n0 = blockIdx.x * 64;
    const int b  = blockIdx.y;
    const int tid = threadIdx.x;
    const float* src = (blockIdx.z == 0 ? input : tg) + (size_t)b * CDIM * NDIM;
    const float zscale = (blockIdx.z == 0) ? 1.0f : 1.44269504f;

    #pragma unroll
    for (int i = 0; i < 8; ++i) {
        int f = tid + i * 256;
        int c = f >> 4, j4 = f & 15;
        float4 v = *(const float4*)(src + (size_t)c * NDIM + n0 + j4 * 4);
        Tt[j4 * 4 + 0][c] = v.x;
        Tt[j4 * 4 + 1][c] = v.y;
        Tt[j4 * 4 + 2][c] = v.z;
        Tt[j4 * 4 + 3][c] = v.w;
    }
    __syncthreads();
    {
        int j = tid & 63, part = tid >> 6;
        float ss = 0.f;
        #pragma unroll 8
        for (int c = part * 32; c < part * 32 + 32; ++c) { float x = Tt[j][c]; ss += x * x; }
        psum[part][j] = ss;
    }
    __syncthreads();
    if (tid < 64) {
        float s = psum[0][tid] + psum[1][tid] + psum[2][tid] + psum[3][tid];
        rn[tid] = 1.0f / fmaxf(sqrtf(s), 1e-12f);
    }
    __syncthreads();

    __hip_bfloat16* dstT = (__hip_bfloat16*)((char*)ws + (blockIdx.z == 0 ? KT_OFF : QT_OFF))
                           + ((size_t)b * NDIM + n0) * CDIM;
    #pragma unroll
    for (int i = 0; i < 8; ++i) {
        int f = tid + i * 256;
        int j = f >> 5, c4 = f & 31;
        float r = rn[j] * zscale;
        float4 v = *(const float4*)&Tt[j][c4 * 4];
        uint2 pk; pk.x = pack2bf(v.x * r, v.y * r); pk.y = pack2bf(v.z * r, v.w * r);
        *(uint2*)((unsigned short*)dstT + (size_t)j * CDIM + c4 * 4) = pk;
    }
    if (blockIdx.z == 0) {
        __hip_bfloat16* vb = (__hip_bfloat16*)((char*)ws + VB_OFF) + (size_t)b * CDIM * NDIM + n0;
        #pragma unroll
        for (int i = 0; i < 8; ++i) {
            int f = tid + i * 256;
            int c = f >> 4, j4 = f & 15;
            float x0 = Tt[j4 * 4 + 0][c], x1 = Tt[j4 * 4 + 1][c];
            float x2 = Tt[j4 * 4 + 2][c], x3 = Tt[j4 * 4 + 3][c];
            uint2 pv; pv.x = pack2bf(x0, x1); pv.y = pack2bf(x2, x3);
            *(uint2*)((unsigned short*)vb + (size_t)c * NDIM + j4 * 4) = pv;
        }
    } else if (blockIdx.x == 0 && b == 0) {
        __hip_bfloat16* wT = (__hip_bfloat16*)((char*)ws + WT_OFF);
        float* sc = (float*)((char*)ws + SC_OFF);
        float* bi = (float*)((char*)ws + BI_OFF);
        #pragma unroll
        for (int i = 0; i < 64; ++i) {
            int f = tid + i * 256;
            int c = f >> 7, o = f & 127;
            wT[o * 128 + c] = __hip_bfloat16(wgt[c * 128 + o]);
        }
        if (tid < 128) {
            float inv = rsqrtf(var[tid] + 1e-5f);
            float s = inv * gamma[tid];
            sc[tid] = s;
            bi[tid] = beta[tid] - mean[tid] * s;
        }
    }
}

// ---------------------------------------------------------------------------
// Pass 2 (flash6): 32x32x16 MFMA, register P, body = 128 n (two 64-n halves,
// NO intra-body barrier: S(half1) independent of exp/PV(half0) -> scheduler
// interleaves exp VALU with MFMA). Dbuf 2x64KB, one raw barrier per body
// (32 total), prefetch in flight across the whole body.
// Grid 256 (1 block/CU), batch = bx&7 (XCD-pinned), m-tile 128.
// 512 thr = 8 waves: nt = w&1 (32-n slice per half), mt = w>>1 (32-m).
// K tile [n128][16 slots cc^(n&15)] @bo; V tile [c128][16 slots j^(c&15)]
// @bo+32K; half1: K +16384, V slot^8 (byte ^128).
// Epilogue: slabs 4x16512 @0 (nt-pair combine), sAgg bf16[128][128] @66560,
// direct float4 global stores (no sRes).
// ---------------------------------------------------------------------------
__global__ __launch_bounds__(512, 2) void flash6(const void* __restrict__ ws_,
                                                 float* __restrict__ out) {
    extern __shared__ char smem[];
    const char* ws = (const char*)ws_;
    const __hip_bfloat16* Qt = (const __hip_bfloat16*)(ws + QT_OFF);
    const __hip_bfloat16* Kt = (const __hip_bfloat16*)(ws + KT_OFF);
    const __hip_bfloat16* Vb = (const __hip_bfloat16*)(ws + VB_OFF);
    const __hip_bfloat16* wT = (const __hip_bfloat16*)(ws + WT_OFF);
    const float* scale = (const float*)(ws + SC_OFF);
    const float* bias  = (const float*)(ws + BI_OFF);

    const int bx = blockIdx.x;
    const int b  = bx & 7;
    const int m0 = (bx >> 3) * 128;
    const int tid = threadIdx.x;
    const int w = tid >> 6, lane = tid & 63;
    const int hf = lane >> 5;
    const int l31 = lane & 31;
    const int nt = w & 1;
    const int mt = w >> 1;

    const char* kgb = (const char*)(Kt + (size_t)b * NDIM * CDIM);
    const char* vgb = (const char*)(Vb + (size_t)b * CDIM * NDIM);

    // resident Q B-frags: col m = m0 + mt*32 + l31
    bf16x8 qb[8];
    {
        const char* qrow = (const char*)Qt + ((size_t)b * NDIM + m0 + mt * 32 + l31) * 256 + hf * 16;
        #pragma unroll
        for (int s = 0; s < 8; ++s) qb[s] = *(const bf16x8*)(qrow + s * 32);
    }

    // loop-invariant LDS read offsets
    unsigned kOff[8];
    {
        int nn = nt * 32 + l31;
        #pragma unroll
        for (int s = 0; s < 8; ++s)
            kOff[s] = nn * 256 + (((2 * s + hf) ^ (nn & 15)) * 16);
    }
    unsigned vOff[2][4];
    #pragma unroll
    for (int t = 0; t < 2; ++t)
        #pragma unroll
        for (int ca = 0; ca < 4; ++ca) {
            int c = ca * 32 + l31;
            vOff[t][ca] = 32768 + c * 256 + (((nt * 4 + t * 2 + hf) ^ (c & 15)) * 16);
        }

    // staging source pointers (per-lane swizzled; rounds advance by constants)
    const int t4 = tid >> 4, j16 = tid & 15;
    const int swz = j16 ^ (t4 & 15);
    const char* kSrcP = kgb + t4 * 256 + swz * 16;               // rounds: +i*8192
    const char* vSrcP = vgb + (size_t)t4 * 8192 + swz * 16;      // rounds: +i*262144
    const unsigned kDstB = w * 1024;                             // + lane*16 implicit
    const unsigned vDstB = 32768 + w * 1024;

    f32x16 oacc[4];
    #pragma unroll
    for (int ca = 0; ca < 4; ++ca)
        #pragma unroll
        for (int i = 0; i < 16; ++i) oacc[ca][i] = 0.f;
    float lacc = 0.f;

    // prologue: stage body 0 into buf0
    #pragma unroll
    for (int i = 0; i < 4; ++i) glds16(kSrcP + i * 8192, smem + kDstB + i * 8192);
    #pragma unroll
    for (int i = 0; i < 4; ++i) glds16(vSrcP + (size_t)i * 262144, smem + vDstB + i * 8192);
    kSrcP += 32768; vSrcP += 256;

    auto make_pf = [&](const f32x16& st, bf16x8 pf[2]) {
        unsigned d[8];
        float lsum = 0.f;
        #pragma unroll
        for (int rq = 0; rq < 4; ++rq) {
            float e0 = exp2f(st[rq * 4 + 0]);
            float e1 = exp2f(st[rq * 4 + 1]);
            float e2 = exp2f(st[rq * 4 + 2]);
            float e3 = exp2f(st[rq * 4 + 3]);
            lsum += (e0 + e1) + (e2 + e3);
            d[rq * 2 + 0] = pack2bf(e0, e1);
            d[rq * 2 + 1] = pack2bf(e2, e3);
        }
        lacc += lsum;
        unsigned o[8];
        #pragma unroll
        for (int j = 0; j < 8; ++j) o[j] = (unsigned)__shfl_xor((int)d[j], 32, 64);
        #pragma unroll
        for (int t = 0; t < 2; ++t) {
            u32x4 tv;
            tv.x = hf ? o[4 * t + 2] : d[4 * t + 0];
            tv.y = hf ? o[4 * t + 3] : d[4 * t + 1];
            tv.z = hf ? d[4 * t + 2] : o[4 * t + 0];
            tv.w = hf ? d[4 * t + 3] : o[4 * t + 1];
            pf[t] = __builtin_bit_cast(bf16x8, tv);
        }
    };

    auto body = [&](const unsigned bo, const bool do_pref) {
        // tile(bo) ready (its glds issued one body ago); all prev reads done.
        asm volatile("s_waitcnt vmcnt(0) lgkmcnt(0)\ns_barrier" ::: "memory");
        if (do_pref) {
            const unsigned obo = bo ^ 65536u;
            #pragma unroll
            for (int i = 0; i < 4; ++i)
                glds16(kSrcP + i * 8192, smem + obo + kDstB + i * 8192);
            #pragma unroll
            for (int i = 0; i < 4; ++i)
                glds16(vSrcP + (size_t)i * 262144, smem + obo + vDstB + i * 8192);
            kSrcP += 32768; vSrcP += 256;
        }

        // S for both halves first: S(half1) gives the scheduler an MFMA
        // stream independent of exp/PV(half0).
        f32x16 st0, st1;
        #pragma unroll
        for (int i = 0; i < 16; ++i) { st0[i] = 0.f; st1[i] = 0.f; }
        #pragma unroll
        for (int s = 0; s < 8; ++s) {
            bf16x8 kf = *(const bf16x8*)(smem + bo + kOff[s]);
            st0 = mfma32(kf, qb[s], st0);
        }
        #pragma unroll
        for (int s = 0; s < 8; ++s) {
            bf16x8 kf = *(const bf16x8*)(smem + bo + 16384 + kOff[s]);
            st1 = mfma32(kf, qb[s], st1);
        }

        bf16x8 pf0[2];
        make_pf(st0, pf0);
        #pragma unroll
        for (int t = 0; t < 2; ++t)
            #pragma unroll
            for (int ca = 0; ca < 4; ++ca) {
                bf16x8 vf = *(const bf16x8*)(smem + bo + vOff[t][ca]);
                oacc[ca] = mfma32(vf, pf0[t], oacc[ca]);
            }

        bf16x8 pf1[2];
        make_pf(st1, pf1);
        #pragma unroll
        for (int t = 0; t < 2; ++t)
            #pragma unroll
            for (int ca = 0; ca < 4; ++ca) {
                bf16x8 vf = *(const bf16x8*)(smem + bo + (vOff[t][ca] ^ 128u));
                oacc[ca] = mfma32(vf, pf1[t], oacc[ca]);
            }
    };

    for (int ii = 0; ii < 16; ++ii) {
        body(0u, true);
        body(65536u, ii != 15);
    }

    // ---- epilogue ----
    float lw = lacc + __shfl_xor(lacc, 32, 64);
    __syncthreads();                               // E0: loop fully done
    char* slab = smem + mt * 16512;                // 4 slabs: 16 KB O + 128 B l
    if (nt == 1) {
        float4* dst = (float4*)slab;
        #pragma unroll
        for (int ca = 0; ca < 4; ++ca)
            #pragma unroll
            for (int rq = 0; rq < 4; ++rq) {
                float4 t = { oacc[ca][rq * 4 + 0], oacc[ca][rq * 4 + 1],
                             oacc[ca][rq * 4 + 2], oacc[ca][rq * 4 + 3] };
                dst[(ca * 4 + rq) * 64 + lane] = t;
            }
        if (lane < 32) ((float*)(slab + 16384))[l31] = lw;
    }
    __syncthreads();                               // E1
    char* sAgg = smem + 66560;                     // bf16 [128 m][128 c] swz
    if (nt == 0) {
        float linv = 1.0f / (lw + ((const float*)(slab + 16384))[l31]);
        const float4* srcp = (const float4*)slab;
        int m = mt * 32 + l31;
        char* aggRow = sAgg + m * 256;
        const int mx = (m & 7) << 1;
        #pragma unroll
        for (int ca = 0; ca < 4; ++ca)
            #pragma unroll
            for (int rq = 0; rq < 4; ++rq) {
                float4 ov = srcp[(ca * 4 + rq) * 64 + lane];
                float v0 = (oacc[ca][rq * 4 + 0] + ov.x) * linv;
                float v1 = (oacc[ca][rq * 4 + 1] + ov.y) * linv;
                float v2 = (oacc[ca][rq * 4 + 2] + ov.z) * linv;
                float v3 = (oacc[ca][rq * 4 + 3] + ov.w) * linv;
                int cq = ca * 8 + rq * 2 + hf;
                uint2 pk; pk.x = pack2bf(v0, v1); pk.y = pack2bf(v2, v3);
                *(uint2*)(aggRow + ((cq ^ mx) * 8)) = pk;
            }
    }
    __syncthreads();                               // E2: sAgg ready

    // projection (16x16 MFMA): wave -> m-slice w*16, all 128 o
    const int li = lane & 15, q = lane >> 4;
    const int pm = w * 16 + li;
    f32x4 racc[8];
    #pragma unroll
    for (int ob = 0; ob < 8; ++ob) { racc[ob][0]=0.f; racc[ob][1]=0.f; racc[ob][2]=0.f; racc[ob][3]=0.f; }
    #pragma unroll
    for (int ks = 0; ks < 4; ++ks) {
        int slot8 = ((ks * 4 + q) * 2) ^ ((li & 7) << 1);
        bf16x8 af = *(const bf16x8*)(sAgg + pm * 256 + slot8 * 8);
        #pragma unroll
        for (int ob = 0; ob < 8; ++ob) {
            bf16x8 wf = *(const bf16x8*)((const char*)wT + (ob * 16 + li) * 256 + ks * 64 + q * 16);
            racc[ob] = mfma16(af, wf, racc[ob]);
        }
    }

    // LeakyReLU + BN(eval) + direct stores: racc r=0..3 are 4 consecutive m
    // -> one float4 per (ob); per inst: 16 o-rows x full 64-B segments.
    float* outb = out + (size_t)b * CDIM * NDIM + m0 + w * 16;
    #pragma unroll
    for (int ob = 0; ob < 8; ++ob) {
        int o = ob * 16 + li;
        float sc = scale[o], bi = bias[o];
        float4 vst;
        float v0 = racc[ob][0]; v0 = (v0 >= 0.f) ? v0 : 0.01f * v0; vst.x = v0 * sc + bi;
        float v1 = racc[ob][1]; v1 = (v1 >= 0.f) ? v1 : 0.01f * v1; vst.y = v1 * sc + bi;
        float v2 = racc[ob][2]; v2 = (v2 >= 0.f) ? v2 : 0.01f * v2; vst.z = v2 * sc + bi;
        float v3 = racc[ob][3]; v3 = (v3 >= 0.f) ? v3 : 0.01f * v3; vst.w = v3 * sc + bi;
        *(float4*)(outb + (size_t)o * NDIM + q * 4) = vst;
    }
}

extern "C" void kernel_launch(void* const* d_in, const int* in_sizes, int n_in,
                              void* d_out, int out_size, void* d_ws, size_t ws_size,
                              hipStream_t stream) {
    const float* input  = (const float*)d_in[0];
    const float* tg     = (const float*)d_in[1];
    const float* weight = (const float*)d_in[2];
    const float* gamma  = (const float*)d_in[3];
    const float* beta   = (const float*)d_in[4];
    const float* rmean  = (const float*)d_in[5];
    const float* rvar   = (const float*)d_in[6];
    float* out = (float*)d_out;

    (void)in_sizes; (void)n_in; (void)out_size; (void)ws_size;

    hipFuncSetAttribute(reinterpret_cast<const void*>(flash6),
                        hipFuncAttributeMaxDynamicSharedMemorySize, 131072);

    dim3 gprep(NDIM / 64, BATCH, 2);
    prep_nt<<<gprep, 256, 0, stream>>>(input, tg, weight, gamma, beta, rmean, rvar, d_ws);
    flash6<<<dim3(256), 512, 131072, stream>>>(d_ws, out);
}